// Round 2
// baseline (44048.856 us; speedup 1.0000x reference)
//
#include <hip/hip_runtime.h>
#include <math.h>

#define BB 32
#define NN 577
#define DD 384
#define HD 1536
#define LL 12
#define MP 608   // padded mem/key length AND padded query rows; multiple of 32
#define NRPT 4

typedef __attribute__((ext_vector_type(8))) short bf16x8;
typedef __attribute__((ext_vector_type(4))) float f32x4;

union BU { bf16x8 v; unsigned short s[8]; };

__device__ __forceinline__ unsigned short f2bf(float f){
  unsigned u = __builtin_bit_cast(unsigned, f);
  u += 0x7fffu + ((u >> 16) & 1u);
  return (unsigned short)(u >> 16);
}

// ---------------- elementwise helpers ----------------

// save cls (row 0) of current x into cls slot; overwrite rows 1..N-1 with x_prime
__global__ void reset_k(float* __restrict__ x, const float* __restrict__ xp, float* __restrict__ cls){
  int i = blockIdx.x * 256 + threadIdx.x;
  if (i >= BB*NN*DD) return;
  int d = i % DD;
  int n = (i / DD) % NN;
  int b = i / (NN*DD);
  if (n == 0) cls[b*DD + d] = x[i];
  else x[i] = xp[i];
}

// mem_bf: (B, MP, D) bf16 = [x tokens (N), cls_hist[0..r-1], zeros]
__global__ void fillmem_k(const float* __restrict__ x, const float* __restrict__ cls_hist,
                          unsigned short* __restrict__ mem, int r){
  int i = blockIdx.x * 256 + threadIdx.x;
  if (i >= BB*MP*DD) return;
  int d = i % DD;
  int n = (i / DD) % MP;
  int b = i / (MP*DD);
  float v = 0.f;
  if (n < NN) v = x[((size_t)b*NN + n)*DD + d];
  else if (n < NN + r) v = cls_hist[(size_t)(n-NN)*BB*DD + b*DD + d];
  mem[i] = f2bf(v);
}

// ---------------- LayerNorm: one wave per row of D=384, bf16 out ----------------

__global__ __launch_bounds__(64) void ln_k(const float* __restrict__ in, const float* __restrict__ w,
                                           const float* __restrict__ bias, unsigned short* __restrict__ out){
  int row = blockIdx.x;
  int lane = threadIdx.x;
  const float* p = in + (size_t)row*DD;
  float v[6];
  float s = 0.f;
  #pragma unroll
  for (int i=0;i<6;i++){ v[i] = p[lane + i*64]; s += v[i]; }
  #pragma unroll
  for (int o=32;o;o>>=1) s += __shfl_xor(s, o, 64);
  float mu = s * (1.f/DD);
  float q = 0.f;
  #pragma unroll
  for (int i=0;i<6;i++){ float t = v[i]-mu; q += t*t; }
  #pragma unroll
  for (int o=32;o;o>>=1) q += __shfl_xor(q, o, 64);
  float rs = rsqrtf(q*(1.f/DD) + 1e-6f);
  unsigned short* po = out + (size_t)row*DD;
  #pragma unroll
  for (int i=0;i<6;i++){
    int c = lane + i*64;
    po[c] = f2bf((v[i]-mu)*rs*w[c] + bias[c]);
  }
}

// ---------------- generic GEMM: C[R x Dout] = A[R x K](bf16) @ W[Dout x K]^T + bias ----------------
// W is fp32, converted to bf16 inline (no weight cache -> small workspace).
// wave-per-block, 32x32 tile, mfma_f32_16x16x32_bf16 (verified layouts:
// A[m=lane&15][k=(lane>>4)*8+j], B[k][n=lane&15], C col=lane&15 row=(lane>>4)*4+reg)
// EPI: 0 = fp32 out, 1 = bf16 out, 2 = fp32 out = v*ls[col] + out (in-place residual), 3 = gelu -> bf16

template<int EPI>
__global__ __launch_bounds__(64) void gemm_k(const unsigned short* __restrict__ A,
                                             const float* __restrict__ W,
                                             const float* __restrict__ bias,
                                             int K, int Dout,
                                             float* __restrict__ outF, unsigned short* __restrict__ outB,
                                             const float* __restrict__ ls){
  int lane = threadIdx.x;
  int lr = lane & 15, kg = lane >> 4;
  int col0 = blockIdx.x * 32;
  int row0 = blockIdx.y * 32;

  const unsigned short* a0 = A + (size_t)(row0 + lr)*K + kg*8;
  const unsigned short* a1 = a0 + (size_t)16*K;
  const float* w0 = W + (size_t)(col0 + lr)*K + kg*8;
  const float* w1 = w0 + (size_t)16*K;

  f32x4 z = {0.f,0.f,0.f,0.f};
  f32x4 acc[2][2] = {{z,z},{z,z}};
  for (int k=0; k<K; k+=32){
    bf16x8 av0 = *(const bf16x8*)(a0 + k);
    bf16x8 av1 = *(const bf16x8*)(a1 + k);
    BU b0, b1;
    #pragma unroll
    for (int j=0;j<8;j++){ b0.s[j] = f2bf(w0[k+j]); b1.s[j] = f2bf(w1[k+j]); }
    acc[0][0] = __builtin_amdgcn_mfma_f32_16x16x32_bf16(av0, b0.v, acc[0][0], 0,0,0);
    acc[0][1] = __builtin_amdgcn_mfma_f32_16x16x32_bf16(av0, b1.v, acc[0][1], 0,0,0);
    acc[1][0] = __builtin_amdgcn_mfma_f32_16x16x32_bf16(av1, b0.v, acc[1][0], 0,0,0);
    acc[1][1] = __builtin_amdgcn_mfma_f32_16x16x32_bf16(av1, b1.v, acc[1][1], 0,0,0);
  }
  #pragma unroll
  for (int sm=0;sm<2;sm++)
    #pragma unroll
    for (int sn=0;sn<2;sn++)
      #pragma unroll
      for (int r=0;r<4;r++){
        int row = row0 + sm*16 + kg*4 + r;
        int col = col0 + sn*16 + lr;
        float vv = acc[sm][sn][r] + bias[col];
        size_t idx = (size_t)row*Dout + col;
        if (EPI == 0) outF[idx] = vv;
        else if (EPI == 1) outB[idx] = f2bf(vv);
        else if (EPI == 2) outF[idx] = vv*ls[col] + outF[idx];
        else { float g = 0.5f*vv*(1.f + erff(vv*0.70710678118f)); outB[idx] = f2bf(g); }
      }
}

// ---------------- attention scores: S[b][m][n] = sum_d qb[b,m,d]*kb[b,n,d] ----------------
__global__ __launch_bounds__(64) void qk_k(const unsigned short* __restrict__ qb,
                                           const unsigned short* __restrict__ kb,
                                           float* __restrict__ scores){
  int lane = threadIdx.x;
  int lr = lane & 15, kg = lane >> 4;
  int n0 = blockIdx.x * 32;
  int m0 = blockIdx.y * 32;
  int b  = blockIdx.z;

  int mA0 = m0 + lr;      if (mA0 > NN-1) mA0 = NN-1;   // clamp padded q rows
  int mA1 = m0 + 16 + lr; if (mA1 > NN-1) mA1 = NN-1;
  const unsigned short* a0 = qb + ((size_t)b*NN + mA0)*DD + kg*8;
  const unsigned short* a1 = qb + ((size_t)b*NN + mA1)*DD + kg*8;
  const unsigned short* w0 = kb + ((size_t)b*MP + n0 + lr)*DD + kg*8;
  const unsigned short* w1 = w0 + (size_t)16*DD;

  f32x4 z = {0.f,0.f,0.f,0.f};
  f32x4 acc[2][2] = {{z,z},{z,z}};
  for (int k=0; k<DD; k+=32){
    bf16x8 av0 = *(const bf16x8*)(a0 + k);
    bf16x8 av1 = *(const bf16x8*)(a1 + k);
    bf16x8 bv0 = *(const bf16x8*)(w0 + k);
    bf16x8 bv1 = *(const bf16x8*)(w1 + k);
    acc[0][0] = __builtin_amdgcn_mfma_f32_16x16x32_bf16(av0, bv0, acc[0][0], 0,0,0);
    acc[0][1] = __builtin_amdgcn_mfma_f32_16x16x32_bf16(av0, bv1, acc[0][1], 0,0,0);
    acc[1][0] = __builtin_amdgcn_mfma_f32_16x16x32_bf16(av1, bv0, acc[1][0], 0,0,0);
    acc[1][1] = __builtin_amdgcn_mfma_f32_16x16x32_bf16(av1, bv1, acc[1][1], 0,0,0);
  }
  float* out = scores + (size_t)b*MP*MP;
  #pragma unroll
  for (int sm=0;sm<2;sm++)
    #pragma unroll
    for (int sn=0;sn<2;sn++)
      #pragma unroll
      for (int r=0;r<4;r++){
        int row = m0 + sm*16 + kg*4 + r;
        int col = n0 + sn*16 + lr;
        out[(size_t)row*MP + col] = acc[sm][sn][r];
      }
}

// ---------------- softmax over cols (mask n>=M), P bf16 with zero padding ----------------
__global__ __launch_bounds__(64) void softmax_k(const float* __restrict__ scores,
                                                unsigned short* __restrict__ P, int M){
  int row = blockIdx.x;          // B*MP rows
  int m = row % MP;
  int lane = threadIdx.x;
  unsigned short* po = P + (size_t)row*MP;
  if (m >= NN){
    for (int n = lane; n < MP; n += 64) po[n] = 0;
    return;
  }
  const float* ps = scores + (size_t)row*MP;
  const float scale = 0.05103103588f;  // 1/sqrt(384)
  float t[10];
  float mx = -INFINITY;
  #pragma unroll
  for (int i=0;i<10;i++){
    int n = lane + i*64;
    float v = (n < M) ? ps[n]*scale : -INFINITY;
    t[i] = v; mx = fmaxf(mx, v);
  }
  #pragma unroll
  for (int o=32;o;o>>=1) mx = fmaxf(mx, __shfl_xor(mx, o, 64));
  float s = 0.f;
  #pragma unroll
  for (int i=0;i<10;i++){
    int n = lane + i*64;
    float e = (n < M) ? expf(t[i]-mx) : 0.f;
    t[i] = e; s += e;
  }
  #pragma unroll
  for (int o=32;o;o>>=1) s += __shfl_xor(s, o, 64);
  float inv = 1.f / s;
  #pragma unroll
  for (int i=0;i<10;i++){
    int n = lane + i*64;
    if (n < MP) po[n] = f2bf(t[i]*inv);
  }
}

// ---------------- PV: prod[b,m,d] = sum_n P[b,m,n] * v[b,n,d]  (strided v gather) ----------------
__global__ __launch_bounds__(64) void pv_k(const unsigned short* __restrict__ P,
                                           const unsigned short* __restrict__ vb,
                                           float* __restrict__ prod){
  int lane = threadIdx.x;
  int lr = lane & 15, kg = lane >> 4;
  int d0t = blockIdx.x * 32;
  int m0  = blockIdx.y * 32;
  int b   = blockIdx.z;

  const unsigned short* a0 = P + ((size_t)b*MP + m0 + lr)*MP + kg*8;
  const unsigned short* a1 = a0 + (size_t)16*MP;
  const unsigned short* vbase = vb + (size_t)b*MP*DD;
  int d0 = d0t + lr, d1 = d0 + 16;

  f32x4 z = {0.f,0.f,0.f,0.f};
  f32x4 acc[2][2] = {{z,z},{z,z}};
  for (int k=0; k<MP; k+=32){
    bf16x8 av0 = *(const bf16x8*)(a0 + k);
    bf16x8 av1 = *(const bf16x8*)(a1 + k);
    BU b0, b1;
    #pragma unroll
    for (int j=0;j<8;j++){
      size_t kk = (size_t)(k + kg*8 + j)*DD;
      b0.s[j] = vbase[kk + d0];
      b1.s[j] = vbase[kk + d1];
    }
    acc[0][0] = __builtin_amdgcn_mfma_f32_16x16x32_bf16(av0, b0.v, acc[0][0], 0,0,0);
    acc[0][1] = __builtin_amdgcn_mfma_f32_16x16x32_bf16(av0, b1.v, acc[0][1], 0,0,0);
    acc[1][0] = __builtin_amdgcn_mfma_f32_16x16x32_bf16(av1, b0.v, acc[1][0], 0,0,0);
    acc[1][1] = __builtin_amdgcn_mfma_f32_16x16x32_bf16(av1, b1.v, acc[1][1], 0,0,0);
  }
  #pragma unroll
  for (int sm=0;sm<2;sm++)
    #pragma unroll
    for (int sn=0;sn<2;sn++)
      #pragma unroll
      for (int r=0;r<4;r++){
        int row = m0 + sm*16 + kg*4 + r;
        int col = d0t + sn*16 + lr;
        if (row < NN) prod[((size_t)b*NN + row)*DD + col] = acc[sm][sn][r];
      }
}

// ---------------- launcher ----------------

extern "C" void kernel_launch(void* const* d_in, const int* in_sizes, int n_in,
                              void* d_out, int out_size, void* d_ws, size_t ws_size,
                              hipStream_t stream){
  const float* x_in = (const float*)d_in[0];
  const float* n1w  = (const float*)d_in[1];
  const float* n1b  = (const float*)d_in[2];
  const float* qkvw = (const float*)d_in[3];
  const float* qkvb = (const float*)d_in[4];
  const float* qnw  = (const float*)d_in[5];
  const float* qnb  = (const float*)d_in[6];
  const float* knw  = (const float*)d_in[7];
  const float* knb  = (const float*)d_in[8];
  const float* anw  = (const float*)d_in[9];
  const float* anb  = (const float*)d_in[10];
  const float* pw   = (const float*)d_in[11];
  const float* pb   = (const float*)d_in[12];
  const float* ls1  = (const float*)d_in[13];
  const float* n2w  = (const float*)d_in[14];
  const float* n2b  = (const float*)d_in[15];
  const float* f1w  = (const float*)d_in[16];
  const float* f1b  = (const float*)d_in[17];
  const float* f2w  = (const float*)d_in[18];
  const float* f2bb = (const float*)d_in[19];
  const float* ls2  = (const float*)d_in[20];

  // ---- workspace layout (lifetime-overlapped slabs; total ~118 MB) ----
  char* ws = (char*)d_ws;
  size_t off = 0;
  auto alloc = [&](size_t bytes)->char* {
    char* p = ws + off;
    off = (off + bytes + 255) & ~(size_t)255;
    return p;
  };

  const size_t QF_B   = (size_t)BB*NN*DD*4;   // 28.4 MB
  const size_t KF_B   = (size_t)BB*MP*DD*4;   // 29.9 MB
  const size_t XN_B   = (size_t)BB*NN*DD*2;   // 14.2 MB
  const size_t KB_B   = (size_t)BB*MP*DD*2;   // 14.9 MB
  const size_t HSTRIP_ROWS = 145*32;          // max strip rows
  const size_t H_B    = HSTRIP_ROWS*HD*2;     // 14.25 MB

  float*          cls_h  = (float*)         alloc((size_t)NRPT*BB*DD*4);
  unsigned short* mem_bf = (unsigned short*)alloc(KB_B);
  unsigned short* vbuf   = (unsigned short*)alloc(KB_B);
  char*           slabF  = alloc(QF_B + KF_B);                 // 58.3 MB
  char*           slabB  = alloc(XN_B + (KB_B > H_B ? KB_B : H_B)); // 29.1 MB

  // slabF timeline: [qf@0, kf@QF_B] -> [scores@0 (47.3MB)] -> [prodf@0]
  float*          qf     = (float*)slabF;
  float*          kf     = (float*)(slabF + QF_B);
  float*          scores = (float*)slabF;
  float*          prodf  = (float*)slabF;
  // slabB timeline: [xn@0] -> [qb@0, kb@XN_B] -> [P@0 (23.7MB)] -> [prod_bf@0] -> [x2@0, h@XN_B]
  unsigned short* xn_bf   = (unsigned short*)slabB;
  unsigned short* qb      = (unsigned short*)slabB;
  unsigned short* kb      = (unsigned short*)(slabB + XN_B);
  unsigned short* Pbf     = (unsigned short*)slabB;
  unsigned short* prod_bf = (unsigned short*)slabB;
  unsigned short* x2_bf   = (unsigned short*)slabB;
  unsigned short* h_bf    = (unsigned short*)(slabB + XN_B);

  float* xf = (float*)d_out;        // fp32 x lives in d_out

  auto cg = [](size_t n){ return dim3((unsigned)((n + 255) / 256)); };

  hipMemcpyAsync(xf, x_in, (size_t)BB*NN*DD*4, hipMemcpyDeviceToDevice, stream);

  // MLP row-strips: 577 row-tiles split as 145/144/144/144
  const int tsplit[5] = {0, 145, 289, 433, 577};

  for (int r = 0; r < NRPT; r++){
    int M = NN + r;
    reset_k<<<cg((size_t)BB*NN*DD),256,0,stream>>>(xf, x_in, cls_h + (size_t)r*BB*DD);
    fillmem_k<<<cg((size_t)BB*MP*DD),256,0,stream>>>(xf, cls_h, mem_bf, r);
    for (int l = 0; l < LL; l++){
      ln_k<<<BB*NN,64,0,stream>>>(xf, n1w + l*DD, n1b + l*DD, xn_bf);
      gemm_k<0><<<dim3(DD/32, BB*NN/32),64,0,stream>>>(xn_bf,  qkvw + (size_t)l*3*DD*DD,           qkvb + l*3*DD,        DD, DD, qf, nullptr, nullptr);
      gemm_k<0><<<dim3(DD/32, BB*MP/32),64,0,stream>>>(mem_bf, qkvw + (size_t)l*3*DD*DD + DD*DD,   qkvb + l*3*DD + DD,   DD, DD, kf, nullptr, nullptr);
      gemm_k<1><<<dim3(DD/32, BB*MP/32),64,0,stream>>>(mem_bf, qkvw + (size_t)l*3*DD*DD + 2*DD*DD, qkvb + l*3*DD + 2*DD, DD, DD, nullptr, vbuf, nullptr);
      ln_k<<<BB*NN,64,0,stream>>>(qf, qnw + l*DD, qnb + l*DD, qb);
      ln_k<<<BB*MP,64,0,stream>>>(kf, knw + l*DD, knb + l*DD, kb);
      qk_k<<<dim3(MP/32, MP/32, BB),64,0,stream>>>(qb, kb, scores);
      softmax_k<<<BB*MP,64,0,stream>>>(scores, Pbf, M);
      pv_k<<<dim3(DD/32, MP/32, BB),64,0,stream>>>(Pbf, vbuf, prodf);
      ln_k<<<BB*NN,64,0,stream>>>(prodf, anw + l*DD, anb + l*DD, prod_bf);
      gemm_k<2><<<dim3(DD/32, BB*NN/32),64,0,stream>>>(prod_bf, pw + (size_t)l*DD*DD, pb + l*DD, DD, DD, xf, nullptr, ls1 + l*DD);
      ln_k<<<BB*NN,64,0,stream>>>(xf, n2w + l*DD, n2b + l*DD, x2_bf);
      for (int s = 0; s < 4; s++){
        int t0 = tsplit[s], t1 = tsplit[s+1];
        int tiles = t1 - t0;
        size_t row0 = (size_t)t0 * 32;
        gemm_k<3><<<dim3(HD/32, tiles),64,0,stream>>>(x2_bf + row0*DD, f1w + (size_t)l*HD*DD, f1b + l*HD, DD, HD, nullptr, h_bf, nullptr);
        gemm_k<2><<<dim3(DD/32, tiles),64,0,stream>>>(h_bf, f2w + (size_t)l*DD*HD, f2bb + l*DD, HD, DD, xf + row0*DD, nullptr, ls2 + l*DD);
      }
    }
  }
}

// Round 3
// 18464.726 us; speedup vs baseline: 2.3856x; 2.3856x over previous
//
#include <hip/hip_runtime.h>
#include <math.h>

#define BB 32
#define NN 577
#define DD 384
#define HD 1536
#define LL 12
#define MP 608   // padded mem/key length; multiple of 32
#define NRPT 4

typedef __attribute__((ext_vector_type(8))) short bf16x8;
typedef __attribute__((ext_vector_type(4))) float f32x4;

__device__ __forceinline__ unsigned short f2bf(float f){
  unsigned u = __builtin_bit_cast(unsigned, f);
  u += 0x7fffu + ((u >> 16) & 1u);
  return (unsigned short)(u >> 16);
}
__device__ __forceinline__ float bf2f(unsigned short s){
  unsigned u = ((unsigned)s) << 16;
  return __builtin_bit_cast(float, u);
}

// async global->LDS, 16B per lane; lds must be wave-uniform
__device__ __forceinline__ void async16(void* lds, const void* g){
  __builtin_amdgcn_global_load_lds(
      (const __attribute__((address_space(1))) unsigned int*)g,
      (__attribute__((address_space(3))) unsigned int*)lds, 16, 0, 0);
}

// ---------------- elementwise helpers ----------------

__global__ void reset_k(float* __restrict__ x, const float* __restrict__ xp, float* __restrict__ cls){
  int i = blockIdx.x * 256 + threadIdx.x;
  if (i >= BB*NN*DD) return;
  int d = i % DD;
  int n = (i / DD) % NN;
  int b = i / (NN*DD);
  if (n == 0) cls[b*DD + d] = x[i];
  else x[i] = xp[i];
}

__global__ void fillmem_k(const float* __restrict__ x, const float* __restrict__ cls_hist,
                          unsigned short* __restrict__ mem, int r){
  int i = blockIdx.x * 256 + threadIdx.x;
  if (i >= BB*MP*DD) return;
  int d = i % DD;
  int n = (i / DD) % MP;
  int b = i / (MP*DD);
  float v = 0.f;
  if (n < NN) v = x[((size_t)b*NN + n)*DD + d];
  else if (n < NN + r) v = cls_hist[(size_t)(n-NN)*BB*DD + b*DD + d];
  mem[i] = f2bf(v);
}

// per-layer weight cast fp32 -> bf16 into wbuf [qkv | proj | fc1 | fc2]
__global__ void castL_k(const float* __restrict__ qkvw, const float* __restrict__ pw,
                        const float* __restrict__ f1w, const float* __restrict__ f2w,
                        unsigned short* __restrict__ wbuf){
  int i = blockIdx.x * 256 + threadIdx.x;
  const int QKV = 3*DD*DD;          // 442368
  const int PRJ = DD*DD;            // 147456
  const int F1  = HD*DD;            // 589824
  const int TOT = QKV + PRJ + 2*F1; // 1769472
  if (i >= TOT) return;
  float v;
  if (i < QKV) v = qkvw[i];
  else if (i < QKV+PRJ) v = pw[i-QKV];
  else if (i < QKV+PRJ+F1) v = f1w[i-QKV-PRJ];
  else v = f2w[i-QKV-PRJ-F1];
  wbuf[i] = f2bf(v);
}

// ---------------- LayerNorm: one wave per row of D=384, bf16 out ----------------

template<typename T>
__global__ __launch_bounds__(64) void ln_k(const T* __restrict__ in, const float* __restrict__ w,
                                           const float* __restrict__ bias, unsigned short* __restrict__ out){
  int row = blockIdx.x;
  int lane = threadIdx.x;
  const T* p = in + (size_t)row*DD;
  float v[6];
  float s = 0.f;
  #pragma unroll
  for (int i=0;i<6;i++){
    float t;
    if (sizeof(T) == 4) t = (float)p[lane + i*64];
    else t = bf2f((unsigned short)p[lane + i*64]);
    v[i] = t; s += t;
  }
  #pragma unroll
  for (int o=32;o;o>>=1) s += __shfl_xor(s, o, 64);
  float mu = s * (1.f/DD);
  float q = 0.f;
  #pragma unroll
  for (int i=0;i<6;i++){ float t = v[i]-mu; q += t*t; }
  #pragma unroll
  for (int o=32;o;o>>=1) q += __shfl_xor(q, o, 64);
  float rs = rsqrtf(q*(1.f/DD) + 1e-6f);
  unsigned short* po = out + (size_t)row*DD;
  #pragma unroll
  for (int i=0;i<6;i++){
    int c = lane + i*64;
    po[c] = f2bf((v[i]-mu)*rs*w[c] + bias[c]);
  }
}

// ---------------- 128x128 LDS-staged GEMM (m97 structure) ----------------
// C[row, col] = sum_k A[row][k] * B[col][k]  (+bias), A and B both K-major bf16.
// 256 threads = 2x2 waves, each wave 64x64 (4x4 frags of 16x16x32 MFMA).
// EPI: 0 = bf16 out (+bias[col] if bias)    (q, k, qk-scores, pv-prod)
//      1 = bf16 out, bias by ROW            (vT = Wv @ mem^T)
//      2 = fp32 residual: out += (v+bias[col])*ls[col]   (proj, fc2)
//      3 = gelu(v+bias[col]) -> bf16        (fc1)

template<int EPI>
__global__ __launch_bounds__(256) void gemm128(
    const unsigned short* __restrict__ A, int lda, int arows, long sA,
    const unsigned short* __restrict__ B, int ldb, int brows, long sB,
    const float* __restrict__ bias,
    int K, int N,
    float* __restrict__ outF, unsigned short* __restrict__ outB,
    int ldo, int orows, long sO,
    const float* __restrict__ ls){

  __shared__ unsigned short a_sh[128*32];
  __shared__ unsigned short b_sh[128*32];

  int tid  = threadIdx.x;
  int wave = tid >> 6, lane = tid & 63;
  int lr = lane & 15, kg = lane >> 4;
  int wm = wave >> 1, wn = wave & 1;
  int z = blockIdx.z;
  int row0 = blockIdx.y * 128;
  int col0 = blockIdx.x * 128;

  const unsigned short* Ab = A + (size_t)z*sA;
  const unsigned short* Bb = B + (size_t)z*sB;

  f32x4 zf = {0.f,0.f,0.f,0.f};
  f32x4 acc[4][4];
  #pragma unroll
  for (int i=0;i<4;i++)
    #pragma unroll
    for (int j=0;j<4;j++) acc[i][j] = zf;

  // precompute clamped staging rows (chunk c = tid + it*256; row = c>>2, kcol=(c&3)*8)
  int ra[2], rb[2], kc[2];
  #pragma unroll
  for (int it=0; it<2; it++){
    int c = tid + it*256;
    int r = row0 + (c>>2); if (r > arows-1) r = arows-1;
    ra[it] = r;
    r = col0 + (c>>2); if (r > brows-1) r = brows-1;
    rb[it] = r;
    kc[it] = (c&3)*8;
  }

  for (int k0 = 0; k0 < K; k0 += 32){
    #pragma unroll
    for (int it=0; it<2; it++){
      unsigned short* la = &a_sh[(it*256 + wave*64)*8];
      unsigned short* lb = &b_sh[(it*256 + wave*64)*8];
      async16(la, Ab + (size_t)ra[it]*lda + k0 + kc[it]);
      async16(lb, Bb + (size_t)rb[it]*ldb + k0 + kc[it]);
    }
    __syncthreads();   // drains vmcnt before barrier (compiler-inserted)
    bf16x8 af[4], bf[4];
    #pragma unroll
    for (int i=0;i<4;i++){
      af[i] = *(const bf16x8*)&a_sh[(wm*64 + i*16 + lr)*32 + kg*8];
      bf[i] = *(const bf16x8*)&b_sh[(wn*64 + i*16 + lr)*32 + kg*8];
    }
    #pragma unroll
    for (int i=0;i<4;i++)
      #pragma unroll
      for (int j=0;j<4;j++)
        acc[i][j] = __builtin_amdgcn_mfma_f32_16x16x32_bf16(af[i], bf[j], acc[i][j], 0,0,0);
    __syncthreads();
  }

  float* oF = outF ? outF + (size_t)z*sO : nullptr;
  unsigned short* oB = outB ? outB + (size_t)z*sO : nullptr;

  #pragma unroll
  for (int mi=0;mi<4;mi++)
    #pragma unroll
    for (int ni=0;ni<4;ni++)
      #pragma unroll
      for (int r=0;r<4;r++){
        int row = row0 + wm*64 + mi*16 + kg*4 + r;
        int col = col0 + wn*64 + ni*16 + lr;
        if (row >= orows || col >= N) continue;
        float vv = acc[mi][ni][r];
        size_t idx = (size_t)row*ldo + col;
        if (EPI == 0){
          if (bias) vv += bias[col];
          oB[idx] = f2bf(vv);
        } else if (EPI == 1){
          vv += bias[row];
          oB[idx] = f2bf(vv);
        } else if (EPI == 2){
          vv += bias[col];
          oF[idx] = vv*ls[col] + oF[idx];
        } else {
          vv += bias[col];
          float g = 0.5f*vv*(1.f + erff(vv*0.70710678118f));
          oB[idx] = f2bf(g);
        }
      }
}

// ---------------- softmax over cols (bf16 in/out, mask n>=M) ----------------
__global__ __launch_bounds__(64) void softmax_k(const unsigned short* __restrict__ S,
                                                unsigned short* __restrict__ P, int M){
  int row = blockIdx.x;          // B*MP rows
  int m = row % MP;
  int lane = threadIdx.x;
  unsigned short* po = P + (size_t)row*MP;
  if (m >= NN){
    for (int n = lane; n < MP; n += 64) po[n] = 0;
    return;
  }
  const unsigned short* ps = S + (size_t)row*MP;
  const float scale = 0.05103103588f;  // 1/sqrt(384)
  float t[10];
  float mx = -INFINITY;
  #pragma unroll
  for (int i=0;i<10;i++){
    int n = lane + i*64;
    float v = (n < M) ? bf2f(ps[n])*scale : -INFINITY;
    t[i] = v; mx = fmaxf(mx, v);
  }
  #pragma unroll
  for (int o=32;o;o>>=1) mx = fmaxf(mx, __shfl_xor(mx, o, 64));
  float s = 0.f;
  #pragma unroll
  for (int i=0;i<10;i++){
    int n = lane + i*64;
    float e = (n < M) ? expf(t[i]-mx) : 0.f;
    t[i] = e; s += e;
  }
  #pragma unroll
  for (int o=32;o;o>>=1) s += __shfl_xor(s, o, 64);
  float inv = 1.f / s;
  #pragma unroll
  for (int i=0;i<10;i++){
    int n = lane + i*64;
    if (n < MP) po[n] = f2bf(t[i]*inv);
  }
}

// ---------------- launcher ----------------

extern "C" void kernel_launch(void* const* d_in, const int* in_sizes, int n_in,
                              void* d_out, int out_size, void* d_ws, size_t ws_size,
                              hipStream_t stream){
  const float* x_in = (const float*)d_in[0];
  const float* n1w  = (const float*)d_in[1];
  const float* n1b  = (const float*)d_in[2];
  const float* qkvw = (const float*)d_in[3];
  const float* qkvb = (const float*)d_in[4];
  const float* qnw  = (const float*)d_in[5];
  const float* qnb  = (const float*)d_in[6];
  const float* knw  = (const float*)d_in[7];
  const float* knb  = (const float*)d_in[8];
  const float* anw  = (const float*)d_in[9];
  const float* anb  = (const float*)d_in[10];
  const float* pw   = (const float*)d_in[11];
  const float* pb   = (const float*)d_in[12];
  const float* ls1  = (const float*)d_in[13];
  const float* n2w  = (const float*)d_in[14];
  const float* n2b  = (const float*)d_in[15];
  const float* f1w  = (const float*)d_in[16];
  const float* f1b  = (const float*)d_in[17];
  const float* f2w  = (const float*)d_in[18];
  const float* f2bb = (const float*)d_in[19];
  const float* ls2  = (const float*)d_in[20];

  // ---- workspace (total ~108 MB) ----
  char* ws = (char*)d_ws;
  size_t off = 0;
  auto alloc = [&](size_t bytes)->char* {
    char* p = ws + off;
    off = (off + bytes + 255) & ~(size_t)255;
    return p;
  };

  const int QKV = 3*DD*DD, PRJ = DD*DD, F1 = HD*DD;
  const size_t WTOT = (size_t)QKV + PRJ + 2*F1;        // 1769472 elems
  const size_t SLOT = (size_t)BB*MP*DD;                // 7471104 elems bf16

  unsigned short* wbuf  = (unsigned short*)alloc(WTOT*2);
  float*          cls_h = (float*)         alloc((size_t)NRPT*BB*DD*4);
  unsigned short* mem_bf= (unsigned short*)alloc(SLOT*2);
  unsigned short* pool  = (unsigned short*)alloc(6*SLOT*2);

  unsigned short* wq = wbuf;                 // [1152][384] rows: q 0..383, k 384..767, v 768..1151
  unsigned short* wp = wbuf + QKV;           // [384][384]
  unsigned short* w1 = wbuf + QKV + PRJ;     // [1536][384]
  unsigned short* w2 = wbuf + QKV + PRJ + F1;// [384][1536]

  // slot pool with lifetime-checked aliasing
  unsigned short* S0 = pool;
  unsigned short* S1 = pool + SLOT;
  unsigned short* S2 = pool + 2*SLOT;
  unsigned short* S3 = pool + 3*SLOT;
  unsigned short* S4 = pool + 4*SLOT;
  unsigned short* S5 = pool + 5*SLOT;

  unsigned short* xn    = S0;   // ln1 out            (steps 1-2)
  unsigned short* qraw  = S1;   // q gemm out         (2-5)
  unsigned short* kraw  = S2;   // k gemm out         (3-6)
  unsigned short* qb    = S3;   // ln q out           (5-7)
  unsigned short* kb    = S4;   // ln k out           (6-7)
  unsigned short* vT    = S5;   // vT gemm out        (4-9)
  unsigned short* Ssc   = S1;   // scores bf16, spans S1S2 (7-8)  [B*MP*MP <= 2*SLOT]
  unsigned short* Pbf   = S3;   // probs bf16, spans S3S4  (8-9)
  unsigned short* prod  = S0;   // pv out             (9-10)
  unsigned short* prodn = S1;   // ln prod out        (10-11)
  unsigned short* x2    = S0;   // ln2 out            (12-13)
  unsigned short* h     = S1;   // fc1 out, spans S1..S4 (13-14) [B*NN*HD <= 4*SLOT]

  float* xf = (float*)d_out;    // fp32 x lives in d_out

  auto cg = [](size_t n){ return dim3((unsigned)((n + 255) / 256)); };

  hipMemcpyAsync(xf, x_in, (size_t)BB*NN*DD*4, hipMemcpyDeviceToDevice, stream);

  const int RT  = (BB*NN + 127)/128;   // 145 row tiles (18464 rows)
  const int RTM = (BB*MP)/128;         // 152 row tiles (19456 rows, exact)

  for (int r = 0; r < NRPT; r++){
    int M = NN + r;
    reset_k<<<cg((size_t)BB*NN*DD),256,0,stream>>>(xf, x_in, cls_h + (size_t)r*BB*DD);
    fillmem_k<<<cg((size_t)BB*MP*DD),256,0,stream>>>(xf, cls_h, mem_bf, r);
    for (int l = 0; l < LL; l++){
      castL_k<<<cg(WTOT),256,0,stream>>>(qkvw + (size_t)l*QKV, pw + (size_t)l*PRJ,
                                         f1w + (size_t)l*F1, f2w + (size_t)l*F1, wbuf);
      // 1: ln1
      ln_k<float><<<BB*NN,64,0,stream>>>(xf, n1w + l*DD, n1b + l*DD, xn);
      // 2: q = xn @ Wq^T + bq
      gemm128<0><<<dim3(3,RT,1),256,0,stream>>>(xn,384,BB*NN,0, wq,384,384,0,
          qkvb + l*3*DD, 384,384, nullptr,qraw,384,BB*NN,0, nullptr);
      // 3: k = mem @ Wk^T + bk
      gemm128<0><<<dim3(3,RTM,1),256,0,stream>>>(mem_bf,384,BB*MP,0, wq + (size_t)DD*DD,384,384,0,
          qkvb + l*3*DD + DD, 384,384, nullptr,kraw,384,BB*MP,0, nullptr);
      // 4: vT[b][d][n] = Wv @ mem^T + bv (bias by row)
      gemm128<1><<<dim3(5,3,BB),256,0,stream>>>(wq + (size_t)2*DD*DD,384,384,0, mem_bf,384,MP,(long)MP*DD,
          qkvb + l*3*DD + 2*DD, 384,MP, nullptr,vT,MP,384,(long)DD*MP, nullptr);
      // 5,6: ln q, ln k
      ln_k<unsigned short><<<BB*NN,64,0,stream>>>(qraw, qnw + l*DD, qnb + l*DD, qb);
      ln_k<unsigned short><<<BB*MP,64,0,stream>>>(kraw, knw + l*DD, knb + l*DD, kb);
      // 7: scores = q @ k^T (batched)
      gemm128<0><<<dim3(5,5,BB),256,0,stream>>>(qb,384,NN,(long)NN*DD, kb,384,MP,(long)MP*DD,
          nullptr, 384,MP, nullptr,Ssc,MP,NN,(long)MP*MP, nullptr);
      // 8: softmax
      softmax_k<<<BB*MP,64,0,stream>>>(Ssc, Pbf, M);
      // 9: prod = P @ vT^T (batched)
      gemm128<0><<<dim3(3,5,BB),256,0,stream>>>(Pbf,MP,MP,(long)MP*MP, vT,MP,DD,(long)DD*MP,
          nullptr, MP,DD, nullptr,prod,DD,NN,(long)NN*DD, nullptr);
      // 10: ln prod
      ln_k<unsigned short><<<BB*NN,64,0,stream>>>(prod, anw + l*DD, anb + l*DD, prodn);
      // 11: x += ls1 * (prodn @ Wp^T + bp)
      gemm128<2><<<dim3(3,RT,1),256,0,stream>>>(prodn,384,BB*NN,0, wp,384,384,0,
          pb + l*DD, 384,384, xf,nullptr,384,BB*NN,0, ls1 + l*DD);
      // 12: ln2
      ln_k<float><<<BB*NN,64,0,stream>>>(xf, n2w + l*DD, n2b + l*DD, x2);
      // 13: h = gelu(x2 @ W1^T + b1)
      gemm128<3><<<dim3(12,RT,1),256,0,stream>>>(x2,384,BB*NN,0, w1,384,HD,0,
          f1b + l*HD, 384,HD, nullptr,h,HD,BB*NN,0, nullptr);
      // 14: x += ls2 * (h @ W2^T + b2)
      gemm128<2><<<dim3(3,RT,1),256,0,stream>>>(h,HD,BB*NN,0, w2,HD,384,0,
          f2bb + l*DD, HD,384, xf,nullptr,384,BB*NN,0, ls2 + l*DD);
    }
  }
}

// Round 4
// 17302.075 us; speedup vs baseline: 2.5459x; 1.0672x over previous
//
#include <hip/hip_runtime.h>
#include <math.h>

#define BB 32
#define NN 577
#define DD 384
#define HD 1536
#define LL 12
#define MP 640   // padded mem/key length; multiple of 64 so all GEMM K are %64==0
#define NRPT 4

typedef __attribute__((ext_vector_type(8))) short bf16x8;
typedef __attribute__((ext_vector_type(4))) float f32x4;

__device__ __forceinline__ unsigned short f2bf(float f){
  unsigned u = __builtin_bit_cast(unsigned, f);
  u += 0x7fffu + ((u >> 16) & 1u);
  return (unsigned short)(u >> 16);
}
__device__ __forceinline__ float bf2f(unsigned short s){
  unsigned u = ((unsigned)s) << 16;
  return __builtin_bit_cast(float, u);
}

// async global->LDS, 16B per lane; lds must be wave-uniform base (+lane*16 implicit)
__device__ __forceinline__ void async16(void* lds, const void* g){
  __builtin_amdgcn_global_load_lds(
      (const __attribute__((address_space(1))) unsigned int*)g,
      (__attribute__((address_space(3))) unsigned int*)lds, 16, 0, 0);
}

// ---------------- fused repeat-prep: reset x, save cls, build mem (bf16, padded) ----------------
__global__ void prep_k(float* __restrict__ x, const float* __restrict__ xp,
                       float* __restrict__ cls_r, const float* __restrict__ cls_hist,
                       unsigned short* __restrict__ mem, int r){
  int i = blockIdx.x * 256 + threadIdx.x;
  if (i >= BB*MP*DD) return;
  int d = i % DD;
  int n = (i / DD) % MP;
  int b = i / (MP*DD);
  float v;
  if (n == 0){ v = x[(size_t)b*NN*DD + d]; cls_r[b*DD + d] = v; }
  else if (n < NN){ v = xp[((size_t)b*NN + n)*DD + d]; x[((size_t)b*NN + n)*DD + d] = v; }
  else if (n < NN + r){ v = cls_hist[(size_t)(n-NN)*BB*DD + b*DD + d]; }
  else v = 0.f;
  mem[i] = f2bf(v);
}

// per-layer weight cast fp32 -> bf16 into wbuf [qkv | proj | fc1 | fc2]
__global__ void castL_k(const float* __restrict__ qkvw, const float* __restrict__ pw,
                        const float* __restrict__ f1w, const float* __restrict__ f2w,
                        unsigned short* __restrict__ wbuf){
  int i = blockIdx.x * 256 + threadIdx.x;
  const int QKV = 3*DD*DD;
  const int PRJ = DD*DD;
  const int F1  = HD*DD;
  const int TOT = QKV + PRJ + 2*F1;
  if (i >= TOT) return;
  float v;
  if (i < QKV) v = qkvw[i];
  else if (i < QKV+PRJ) v = pw[i-QKV];
  else if (i < QKV+PRJ+F1) v = f1w[i-QKV-PRJ];
  else v = f2w[i-QKV-PRJ-F1];
  wbuf[i] = f2bf(v);
}

// ---------------- LayerNorm: 4 rows per 256-thread block (1 wave/row), bf16 out ----------------
template<typename T>
__global__ __launch_bounds__(256) void ln4_k(const T* __restrict__ in, const float* __restrict__ w,
                                             const float* __restrict__ bias, unsigned short* __restrict__ out,
                                             int nrows){
  int row = blockIdx.x*4 + (threadIdx.x >> 6);
  if (row >= nrows) return;
  int lane = threadIdx.x & 63;
  const T* p = in + (size_t)row*DD;
  float v[6];
  float s = 0.f;
  #pragma unroll
  for (int i=0;i<6;i++){
    float t;
    if (sizeof(T) == 4) t = (float)p[lane + i*64];
    else t = bf2f((unsigned short)p[lane + i*64]);
    v[i] = t; s += t;
  }
  #pragma unroll
  for (int o=32;o;o>>=1) s += __shfl_xor(s, o, 64);
  float mu = s * (1.f/DD);
  float q = 0.f;
  #pragma unroll
  for (int i=0;i<6;i++){ float t = v[i]-mu; q += t*t; }
  #pragma unroll
  for (int o=32;o;o>>=1) q += __shfl_xor(q, o, 64);
  float rs = rsqrtf(q*(1.f/DD) + 1e-6f);
  unsigned short* po = out + (size_t)row*DD;
  #pragma unroll
  for (int i=0;i<6;i++){
    int c = lane + i*64;
    po[c] = f2bf((v[i]-mu)*rs*w[c] + bias[c]);
  }
}

// ---------------- 128x128 LDS-staged GEMM, BK=64 (two 32-k panels) ----------------
// C[row, col] = sum_k A[row][k] * B[col][k]  (+bias), A and B both K-major bf16.
// 256 threads = 2x2 waves, each wave 64x64 (4x4 frags of 16x16x32 MFMA).
// K must be a multiple of 64.
// EPI: 0 = bf16 out (+bias[col] if bias)
//      1 = bf16 out, bias by ROW            (vT = Wv @ mem^T)
//      2 = fp32 residual: out += (v+bias[col])*ls[col]
//      3 = gelu(v+bias[col]) -> bf16

template<int EPI>
__global__ __launch_bounds__(256) void gemm128(
    const unsigned short* __restrict__ A, int lda, int arows, long sA,
    const unsigned short* __restrict__ B, int ldb, int brows, long sB,
    const float* __restrict__ bias,
    int K, int N,
    float* __restrict__ outF, unsigned short* __restrict__ outB,
    int ldo, int orows, long sO,
    const float* __restrict__ ls){

  __shared__ unsigned short a_sh[2][128*32];
  __shared__ unsigned short b_sh[2][128*32];

  int tid  = threadIdx.x;
  int wave = tid >> 6, lane = tid & 63;
  int lr = lane & 15, kg = lane >> 4;
  int wm = wave >> 1, wn = wave & 1;
  int z = blockIdx.z;
  int row0 = blockIdx.y * 128;
  int col0 = blockIdx.x * 128;

  const unsigned short* Ab = A + (size_t)z*sA;
  const unsigned short* Bb = B + (size_t)z*sB;

  f32x4 zf = {0.f,0.f,0.f,0.f};
  f32x4 acc[4][4];
  #pragma unroll
  for (int i=0;i<4;i++)
    #pragma unroll
    for (int j=0;j<4;j++) acc[i][j] = zf;

  // staging chunks: c = tid + it*256; row = c>>2, k-offset = (c&3)*8 elems (32-k panel)
  int ra[2], rb[2], kc[2];
  #pragma unroll
  for (int it=0; it<2; it++){
    int c = tid + it*256;
    int r = row0 + (c>>2); if (r > arows-1) r = arows-1;
    ra[it] = r;
    r = col0 + (c>>2); if (r > brows-1) r = brows-1;
    rb[it] = r;
    kc[it] = (c&3)*8;
  }

  for (int k0 = 0; k0 < K; k0 += 64){
    #pragma unroll
    for (int p=0;p<2;p++){
      #pragma unroll
      for (int it=0; it<2; it++){
        unsigned short* la = &a_sh[p][(it*256 + wave*64)*8];
        unsigned short* lb = &b_sh[p][(it*256 + wave*64)*8];
        async16(la, Ab + (size_t)ra[it]*lda + k0 + p*32 + kc[it]);
        async16(lb, Bb + (size_t)rb[it]*ldb + k0 + p*32 + kc[it]);
      }
    }
    __syncthreads();
    #pragma unroll
    for (int p=0;p<2;p++){
      bf16x8 af[4], bfr[4];
      #pragma unroll
      for (int i=0;i<4;i++){
        af[i]  = *(const bf16x8*)&a_sh[p][(wm*64 + i*16 + lr)*32 + kg*8];
        bfr[i] = *(const bf16x8*)&b_sh[p][(wn*64 + i*16 + lr)*32 + kg*8];
      }
      #pragma unroll
      for (int i=0;i<4;i++)
        #pragma unroll
        for (int j=0;j<4;j++)
          acc[i][j] = __builtin_amdgcn_mfma_f32_16x16x32_bf16(af[i], bfr[j], acc[i][j], 0,0,0);
    }
    __syncthreads();
  }

  float* oF = outF ? outF + (size_t)z*sO : nullptr;
  unsigned short* oB = outB ? outB + (size_t)z*sO : nullptr;

  #pragma unroll
  for (int mi=0;mi<4;mi++)
    #pragma unroll
    for (int ni=0;ni<4;ni++)
      #pragma unroll
      for (int r=0;r<4;r++){
        int row = row0 + wm*64 + mi*16 + kg*4 + r;
        int col = col0 + wn*64 + ni*16 + lr;
        if (row >= orows || col >= N) continue;
        float vv = acc[mi][ni][r];
        size_t idx = (size_t)row*ldo + col;
        if (EPI == 0){
          if (bias) vv += bias[col];
          oB[idx] = f2bf(vv);
        } else if (EPI == 1){
          vv += bias[row];
          oB[idx] = f2bf(vv);
        } else if (EPI == 2){
          vv += bias[col];
          oF[idx] = vv*ls[col] + oF[idx];
        } else {
          vv += bias[col];
          float g = 0.5f*vv*(1.f + erff(vv*0.70710678118f));
          oB[idx] = f2bf(g);
        }
      }
}

// ---------------- softmax: 4 rows per block (bf16 in/out, mask n>=M) ----------------
__global__ __launch_bounds__(256) void softmax4_k(const unsigned short* __restrict__ S,
                                                  unsigned short* __restrict__ P, int M){
  int row = blockIdx.x*4 + (threadIdx.x >> 6);   // B*MP rows
  int m = row % MP;
  int lane = threadIdx.x & 63;
  unsigned short* po = P + (size_t)row*MP;
  if (m >= NN){
    for (int n = lane; n < MP; n += 64) po[n] = 0;
    return;
  }
  const unsigned short* ps = S + (size_t)row*MP;
  const float scale = 0.05103103588f;  // 1/sqrt(384)
  float t[10];
  float mx = -INFINITY;
  #pragma unroll
  for (int i=0;i<10;i++){
    int n = lane + i*64;
    float v = (n < M) ? bf2f(ps[n])*scale : -INFINITY;
    t[i] = v; mx = fmaxf(mx, v);
  }
  #pragma unroll
  for (int o=32;o;o>>=1) mx = fmaxf(mx, __shfl_xor(mx, o, 64));
  float s = 0.f;
  #pragma unroll
  for (int i=0;i<10;i++){
    int n = lane + i*64;
    float e = (n < M) ? expf(t[i]-mx) : 0.f;
    t[i] = e; s += e;
  }
  #pragma unroll
  for (int o=32;o;o>>=1) s += __shfl_xor(s, o, 64);
  float inv = 1.f / s;
  #pragma unroll
  for (int i=0;i<10;i++){
    int n = lane + i*64;
    po[n] = f2bf(t[i]*inv);
  }
}

// ---------------- launcher ----------------

extern "C" void kernel_launch(void* const* d_in, const int* in_sizes, int n_in,
                              void* d_out, int out_size, void* d_ws, size_t ws_size,
                              hipStream_t stream){
  const float* x_in = (const float*)d_in[0];
  const float* n1w  = (const float*)d_in[1];
  const float* n1b  = (const float*)d_in[2];
  const float* qkvw = (const float*)d_in[3];
  const float* qkvb = (const float*)d_in[4];
  const float* qnw  = (const float*)d_in[5];
  const float* qnb  = (const float*)d_in[6];
  const float* knw  = (const float*)d_in[7];
  const float* knb  = (const float*)d_in[8];
  const float* anw  = (const float*)d_in[9];
  const float* anb  = (const float*)d_in[10];
  const float* pw   = (const float*)d_in[11];
  const float* pb   = (const float*)d_in[12];
  const float* ls1  = (const float*)d_in[13];
  const float* n2w  = (const float*)d_in[14];
  const float* n2b  = (const float*)d_in[15];
  const float* f1w  = (const float*)d_in[16];
  const float* f1b  = (const float*)d_in[17];
  const float* f2w  = (const float*)d_in[18];
  const float* f2bb = (const float*)d_in[19];
  const float* ls2  = (const float*)d_in[20];

  // ---- workspace (total ~114 MB) ----
  char* ws = (char*)d_ws;
  size_t off = 0;
  auto alloc = [&](size_t bytes)->char* {
    char* p = ws + off;
    off = (off + bytes + 255) & ~(size_t)255;
    return p;
  };

  const int QKV = 3*DD*DD, PRJ = DD*DD, F1 = HD*DD;
  const size_t WTOT = (size_t)QKV + PRJ + 2*F1;        // 1769472 elems
  const size_t SLOT = (size_t)BB*MP*DD;                // 7864320 elems bf16

  unsigned short* wbuf  = (unsigned short*)alloc(WTOT*2);
  float*          cls_h = (float*)         alloc((size_t)NRPT*BB*DD*4);
  unsigned short* mem_bf= (unsigned short*)alloc(SLOT*2);
  unsigned short* pool  = (unsigned short*)alloc(6*SLOT*2);

  unsigned short* wq = wbuf;                 // [1152][384]
  unsigned short* wp = wbuf + QKV;           // [384][384]
  unsigned short* w1 = wbuf + QKV + PRJ;     // [1536][384]
  unsigned short* w2 = wbuf + QKV + PRJ + F1;// [384][1536]

  unsigned short* S0 = pool;
  unsigned short* S1 = pool + SLOT;
  unsigned short* S2 = pool + 2*SLOT;
  unsigned short* S3 = pool + 3*SLOT;
  unsigned short* S4 = pool + 4*SLOT;
  unsigned short* S5 = pool + 5*SLOT;

  unsigned short* xn    = S0;   // ln1 out            (1-2)
  unsigned short* qraw  = S1;   // q gemm out         (2-5)
  unsigned short* kraw  = S2;   // k gemm out         (3-6)
  unsigned short* qb    = S3;   // ln q out           (5-7)
  unsigned short* kb    = S4;   // ln k out           (6-7)
  unsigned short* vT    = S5;   // vT gemm out        (4-9)
  unsigned short* Ssc   = S1;   // scores, spans S1S2 (7-8)  [B*MP*MP <= 2*SLOT]
  unsigned short* Pbf   = S3;   // probs, spans S3S4  (8-9)
  unsigned short* prod  = S0;   // pv out             (9-10)
  unsigned short* prodn = S1;   // ln prod out        (10-11)
  unsigned short* x2    = S0;   // ln2 out            (12-13)
  unsigned short* h     = S1;   // fc1 out, S1..S4    (13-14) [B*NN*HD <= 4*SLOT]

  float* xf = (float*)d_out;    // fp32 x lives in d_out

  auto cg = [](size_t n){ return dim3((unsigned)((n + 255) / 256)); };

  hipMemcpyAsync(xf, x_in, (size_t)BB*NN*DD*4, hipMemcpyDeviceToDevice, stream);

  const int RT   = (BB*NN + 127)/128;   // 145 row tiles
  const int RTM  = (BB*MP)/128;         // 160 row tiles (exact)
  const int QR   = BB*NN;               // 18464
  const int KR   = BB*MP;               // 20480

  for (int r = 0; r < NRPT; r++){
    int M = NN + r;
    prep_k<<<cg((size_t)BB*MP*DD),256,0,stream>>>(xf, x_in, cls_h + (size_t)r*BB*DD, cls_h, mem_bf, r);
    for (int l = 0; l < LL; l++){
      castL_k<<<cg(WTOT),256,0,stream>>>(qkvw + (size_t)l*QKV, pw + (size_t)l*PRJ,
                                         f1w + (size_t)l*F1, f2w + (size_t)l*F1, wbuf);
      // 1: ln1
      ln4_k<float><<<cg((size_t)QR*64),256,0,stream>>>(xf, n1w + l*DD, n1b + l*DD, xn, QR);
      // 2: q = xn @ Wq^T + bq
      gemm128<0><<<dim3(3,RT,1),256,0,stream>>>(xn,384,QR,0, wq,384,384,0,
          qkvb + l*3*DD, 384,384, nullptr,qraw,384,QR,0, nullptr);
      // 3: k = mem @ Wk^T + bk
      gemm128<0><<<dim3(3,RTM,1),256,0,stream>>>(mem_bf,384,KR,0, wq + (size_t)DD*DD,384,384,0,
          qkvb + l*3*DD + DD, 384,384, nullptr,kraw,384,KR,0, nullptr);
      // 4: vT[b][d][n] = Wv @ mem^T + bv (bias by row)
      gemm128<1><<<dim3(MP/128,3,BB),256,0,stream>>>(wq + (size_t)2*DD*DD,384,384,0, mem_bf,384,MP,(long)MP*DD,
          qkvb + l*3*DD + 2*DD, 384,MP, nullptr,vT,MP,384,(long)DD*MP, nullptr);
      // 5,6: ln q, ln k
      ln4_k<unsigned short><<<cg((size_t)QR*64),256,0,stream>>>(qraw, qnw + l*DD, qnb + l*DD, qb, QR);
      ln4_k<unsigned short><<<cg((size_t)KR*64),256,0,stream>>>(kraw, knw + l*DD, knb + l*DD, kb, KR);
      // 7: scores = q @ k^T (batched)
      gemm128<0><<<dim3(MP/128,MP/128,BB),256,0,stream>>>(qb,384,NN,(long)NN*DD, kb,384,MP,(long)MP*DD,
          nullptr, 384,MP, nullptr,Ssc,MP,NN,(long)MP*MP, nullptr);
      // 8: softmax
      softmax4_k<<<KR/4,256,0,stream>>>(Ssc, Pbf, M);
      // 9: prod = P @ vT^T (batched)
      gemm128<0><<<dim3(3,MP/128,BB),256,0,stream>>>(Pbf,MP,MP,(long)MP*MP, vT,MP,DD,(long)DD*MP,
          nullptr, MP,DD, nullptr,prod,DD,NN,(long)NN*DD, nullptr);
      // 10: ln prod
      ln4_k<unsigned short><<<cg((size_t)QR*64),256,0,stream>>>(prod, anw + l*DD, anb + l*DD, prodn, QR);
      // 11: x += ls1 * (prodn @ Wp^T + bp)
      gemm128<2><<<dim3(3,RT,1),256,0,stream>>>(prodn,384,QR,0, wp,384,384,0,
          pb + l*DD, 384,384, xf,nullptr,384,QR,0, ls1 + l*DD);
      // 12: ln2
      ln4_k<float><<<cg((size_t)QR*64),256,0,stream>>>(xf, n2w + l*DD, n2b + l*DD, x2, QR);
      // 13: h = gelu(x2 @ W1^T + b1)
      gemm128<3><<<dim3(HD/128,RT,1),256,0,stream>>>(x2,384,QR,0, w1,384,HD,0,
          f1b + l*HD, 384,HD, nullptr,h,HD,QR,0, nullptr);
      // 14: x += ls2 * (h @ W2^T + b2)
      gemm128<2><<<dim3(3,RT,1),256,0,stream>>>(h,HD,QR,0, w2,HD,384,0,
          f2bb + l*DD, HD,384, xf,nullptr,384,QR,0, ls2 + l*DD);
    }
  }
}

// Round 5
// 16882.487 us; speedup vs baseline: 2.6091x; 1.0249x over previous
//
#include <hip/hip_runtime.h>
#include <math.h>

#define BB 32
#define NN 577
#define DD 384
#define HD 1536
#define LL 12
#define MP 640   // padded mem/key length; multiple of 64 so all GEMM K are %64==0
#define NRPT 4

typedef __attribute__((ext_vector_type(8))) short bf16x8;
typedef __attribute__((ext_vector_type(4))) float f32x4;

__device__ __forceinline__ unsigned short f2bf(float f){
  unsigned u = __builtin_bit_cast(unsigned, f);
  u += 0x7fffu + ((u >> 16) & 1u);
  return (unsigned short)(u >> 16);
}
__device__ __forceinline__ float bf2f(unsigned short s){
  unsigned u = ((unsigned)s) << 16;
  return __builtin_bit_cast(float, u);
}

// async global->LDS, 16B per lane; lds base wave-uniform + lane*16 implicit
__device__ __forceinline__ void async16(void* lds, const void* g){
  __builtin_amdgcn_global_load_lds(
      (const __attribute__((address_space(1))) unsigned int*)g,
      (__attribute__((address_space(3))) unsigned int*)lds, 16, 0, 0);
}

// ---------------- fused repeat-prep ----------------
__global__ void prep_k(float* __restrict__ x, const float* __restrict__ xp,
                       float* __restrict__ cls_r, const float* __restrict__ cls_hist,
                       unsigned short* __restrict__ mem, int r){
  int i = blockIdx.x * 256 + threadIdx.x;
  if (i >= BB*MP*DD) return;
  int d = i % DD;
  int n = (i / DD) % MP;
  int b = i / (MP*DD);
  float v;
  if (n == 0){ v = x[(size_t)b*NN*DD + d]; cls_r[b*DD + d] = v; }
  else if (n < NN){ v = xp[((size_t)b*NN + n)*DD + d]; x[((size_t)b*NN + n)*DD + d] = v; }
  else if (n < NN + r){ v = cls_hist[(size_t)(n-NN)*BB*DD + b*DD + d]; }
  else v = 0.f;
  mem[i] = f2bf(v);
}

// per-layer weight cast
__global__ void castL_k(const float* __restrict__ qkvw, const float* __restrict__ pw,
                        const float* __restrict__ f1w, const float* __restrict__ f2w,
                        unsigned short* __restrict__ wbuf){
  int i = blockIdx.x * 256 + threadIdx.x;
  const int QKV = 3*DD*DD;
  const int PRJ = DD*DD;
  const int F1  = HD*DD;
  const int TOT = QKV + PRJ + 2*F1;
  if (i >= TOT) return;
  float v;
  if (i < QKV) v = qkvw[i];
  else if (i < QKV+PRJ) v = pw[i-QKV];
  else if (i < QKV+PRJ+F1) v = f1w[i-QKV-PRJ];
  else v = f2w[i-QKV-PRJ-F1];
  wbuf[i] = f2bf(v);
}

// ---------------- LayerNorm: 4 rows per block ----------------
template<typename T>
__global__ __launch_bounds__(256) void ln4_k(const T* __restrict__ in, const float* __restrict__ w,
                                             const float* __restrict__ bias, unsigned short* __restrict__ out,
                                             int nrows){
  int row = blockIdx.x*4 + (threadIdx.x >> 6);
  if (row >= nrows) return;
  int lane = threadIdx.x & 63;
  const T* p = in + (size_t)row*DD;
  float v[6];
  float s = 0.f;
  #pragma unroll
  for (int i=0;i<6;i++){
    float t;
    if (sizeof(T) == 4) t = (float)p[lane + i*64];
    else t = bf2f((unsigned short)p[lane + i*64]);
    v[i] = t; s += t;
  }
  #pragma unroll
  for (int o=32;o;o>>=1) s += __shfl_xor(s, o, 64);
  float mu = s * (1.f/DD);
  float q = 0.f;
  #pragma unroll
  for (int i=0;i<6;i++){ float t = v[i]-mu; q += t*t; }
  #pragma unroll
  for (int o=32;o;o>>=1) q += __shfl_xor(q, o, 64);
  float rs = rsqrtf(q*(1.f/DD) + 1e-6f);
  unsigned short* po = out + (size_t)row*DD;
  #pragma unroll
  for (int i=0;i<6;i++){
    int c = lane + i*64;
    po[c] = f2bf((v[i]-mu)*rs*w[c] + bias[c]);
  }
}

// merged LN for q (scaled by 1/sqrt(D)) and k; row < QR -> q, else k
__global__ __launch_bounds__(256) void lnqk_k(const unsigned short* __restrict__ qraw,
                                              const unsigned short* __restrict__ kraw,
                                              const float* __restrict__ qw, const float* __restrict__ qbias,
                                              const float* __restrict__ kw, const float* __restrict__ kbias,
                                              unsigned short* __restrict__ qo, unsigned short* __restrict__ ko){
  const int QR = BB*NN;
  int row = blockIdx.x*4 + (threadIdx.x >> 6);
  int lane = threadIdx.x & 63;
  bool isq = row < QR;   // QR % 4 == 0: no intra-block divergence
  const unsigned short* p = isq ? qraw + (size_t)row*DD : kraw + (size_t)(row-QR)*DD;
  const float* w  = isq ? qw : kw;
  const float* bs = isq ? qbias : kbias;
  unsigned short* po = isq ? qo + (size_t)row*DD : ko + (size_t)(row-QR)*DD;
  float scale = isq ? 0.05103103588f : 1.0f;  // fold softmax scale into q
  float v[6];
  float s = 0.f;
  #pragma unroll
  for (int i=0;i<6;i++){ float t = bf2f(p[lane + i*64]); v[i] = t; s += t; }
  #pragma unroll
  for (int o=32;o;o>>=1) s += __shfl_xor(s, o, 64);
  float mu = s * (1.f/DD);
  float q = 0.f;
  #pragma unroll
  for (int i=0;i<6;i++){ float t = v[i]-mu; q += t*t; }
  #pragma unroll
  for (int o=32;o;o>>=1) q += __shfl_xor(q, o, 64);
  float rs = rsqrtf(q*(1.f/DD) + 1e-6f);
  #pragma unroll
  for (int i=0;i<6;i++){
    int c = lane + i*64;
    po[c] = f2bf(((v[i]-mu)*rs*w[c] + bs[c]) * scale);
  }
}

// ---------------- 128x128 LDS-staged GEMM, BK=64 ----------------
template<int EPI>
__global__ __launch_bounds__(256) void gemm128(
    const unsigned short* __restrict__ A, int lda, int arows, long sA,
    const unsigned short* __restrict__ B, int ldb, int brows, long sB,
    const float* __restrict__ bias,
    int K, int N,
    float* __restrict__ outF, unsigned short* __restrict__ outB,
    int ldo, int orows, long sO,
    const float* __restrict__ ls){

  __shared__ unsigned short a_sh[2][128*32];
  __shared__ unsigned short b_sh[2][128*32];

  int tid  = threadIdx.x;
  int wave = tid >> 6, lane = tid & 63;
  int lr = lane & 15, kg = lane >> 4;
  int wm = wave >> 1, wn = wave & 1;
  int z = blockIdx.z;
  int row0 = blockIdx.y * 128;
  int col0 = blockIdx.x * 128;

  const unsigned short* Ab = A + (size_t)z*sA;
  const unsigned short* Bb = B + (size_t)z*sB;

  f32x4 zf = {0.f,0.f,0.f,0.f};
  f32x4 acc[4][4];
  #pragma unroll
  for (int i=0;i<4;i++)
    #pragma unroll
    for (int j=0;j<4;j++) acc[i][j] = zf;

  int ra[2], rb[2], kc[2];
  #pragma unroll
  for (int it=0; it<2; it++){
    int c = tid + it*256;
    int r = row0 + (c>>2); if (r > arows-1) r = arows-1;
    ra[it] = r;
    r = col0 + (c>>2); if (r > brows-1) r = brows-1;
    rb[it] = r;
    kc[it] = (c&3)*8;
  }

  for (int k0 = 0; k0 < K; k0 += 64){
    #pragma unroll
    for (int p=0;p<2;p++){
      #pragma unroll
      for (int it=0; it<2; it++){
        unsigned short* la = &a_sh[p][(it*256 + wave*64)*8];
        unsigned short* lb = &b_sh[p][(it*256 + wave*64)*8];
        async16(la, Ab + (size_t)ra[it]*lda + k0 + p*32 + kc[it]);
        async16(lb, Bb + (size_t)rb[it]*ldb + k0 + p*32 + kc[it]);
      }
    }
    __syncthreads();
    #pragma unroll
    for (int p=0;p<2;p++){
      bf16x8 af[4], bfr[4];
      #pragma unroll
      for (int i=0;i<4;i++){
        af[i]  = *(const bf16x8*)&a_sh[p][(wm*64 + i*16 + lr)*32 + kg*8];
        bfr[i] = *(const bf16x8*)&b_sh[p][(wn*64 + i*16 + lr)*32 + kg*8];
      }
      #pragma unroll
      for (int i=0;i<4;i++)
        #pragma unroll
        for (int j=0;j<4;j++)
          acc[i][j] = __builtin_amdgcn_mfma_f32_16x16x32_bf16(af[i], bfr[j], acc[i][j], 0,0,0);
    }
    __syncthreads();
  }

  float* oF = outF ? outF + (size_t)z*sO : nullptr;
  unsigned short* oB = outB ? outB + (size_t)z*sO : nullptr;

  #pragma unroll
  for (int mi=0;mi<4;mi++)
    #pragma unroll
    for (int ni=0;ni<4;ni++)
      #pragma unroll
      for (int r=0;r<4;r++){
        int row = row0 + wm*64 + mi*16 + kg*4 + r;
        int col = col0 + wn*64 + ni*16 + lr;
        if (row >= orows || col >= N) continue;
        float vv = acc[mi][ni][r];
        size_t idx = (size_t)row*ldo + col;
        if (EPI == 0){
          if (bias) vv += bias[col];
          oB[idx] = f2bf(vv);
        } else if (EPI == 1){
          vv += bias[row];
          oB[idx] = f2bf(vv);
        } else if (EPI == 2){
          vv += bias[col];
          oF[idx] = vv*ls[col] + oF[idx];
        } else {
          vv += bias[col];
          float g = 0.5f*vv*(1.f + erff(vv*0.70710678118f));
          oB[idx] = f2bf(g);
        }
      }
}

// ---------------- fused flash attention + an-LayerNorm ----------------
// qs: [B*NN][384] LN'd q pre-scaled by 1/sqrt(D); kb: [B*MP][384] LN'd k;
// vT: [B][384][MP]. out: prodn = LN_an(softmax(qk)@v)  [B*NN][384] bf16.
// Block: 256 thr / 4 waves; 64 q-rows per block; wave w owns rows w*16..w*16+15
// end-to-end (QK strips, online softmax state in regs, O rows, epilogue LN).
// 19 k-tiles of 32 keys (covers cols 0..607 >= max M=580).
__global__ __launch_bounds__(256, 2) void attn_k(
    const unsigned short* __restrict__ qs,
    const unsigned short* __restrict__ kb,
    const unsigned short* __restrict__ vT,
    const float* __restrict__ anw, const float* __restrict__ anb,
    unsigned short* __restrict__ out, int M){

  __shared__ unsigned short k_sh[32*384];   // swizzled: LDS[row][c'] = g[row][c' low3^row&7]
  __shared__ unsigned short v_sh[384*32];   // swizzled: LDS[d][c'] = g[d][c'^ (d&3)]
  __shared__ unsigned short p_sh[64*56];    // P in A-layout, padded stride 56

  int tid = threadIdx.x;
  int wv = tid >> 6, lane = tid & 63;
  int lr = lane & 15, kg = lane >> 4;
  int b = blockIdx.y, qt0 = blockIdx.x * 64;

  // q A-frags in registers: m = lr -> q row = qt0 + wv*16 + lr
  bf16x8 qf[12];
  {
    int qrow = qt0 + wv*16 + lr; if (qrow > NN-1) qrow = NN-1;
    const unsigned short* qp = qs + ((size_t)b*NN + qrow)*DD;
    #pragma unroll
    for (int ks=0; ks<12; ks++) qf[ks] = *(const bf16x8*)(qp + ks*32 + kg*8);
  }

  f32x4 zf = {0.f,0.f,0.f,0.f};
  f32x4 O[24];
  #pragma unroll
  for (int i=0;i<24;i++) O[i] = zf;
  float m_run[4], l_run[4];
  #pragma unroll
  for (int r=0;r<4;r++){ m_run[r] = -INFINITY; l_run[r] = 0.f; }

  for (int kt=0; kt<19; kt++){
    __syncthreads();   // protect LDS from previous iteration's readers
    // stage k-tile: 32 rows x 48 chunks
    #pragma unroll
    for (int i=0;i<6;i++){
      int L = i*256 + tid;
      int row = L/48, c = L%48;
      int gc = (c & ~7) | ((c ^ row) & 7);
      async16(&k_sh[L*8], kb + ((size_t)b*MP + kt*32 + row)*DD + gc*8);
    }
    // stage v-tile: 384 d-rows x 4 chunks
    #pragma unroll
    for (int i=0;i<6;i++){
      int L = i*256 + tid;
      int row = L>>2;
      int gc = (L&3) ^ (row&3);
      async16(&v_sh[L*8], vT + ((size_t)b*DD + row)*MP + kt*32 + gc*8);
    }
    __syncthreads();   // staged data visible

    // QK: wave computes rows wv*16..+15 x 32 keys (2 col tiles)
    f32x4 s[2] = {zf, zf};
    #pragma unroll
    for (int ks=0; ks<12; ks++){
      int c = ks*4 + kg;
      #pragma unroll
      for (int nk=0; nk<2; nk++){
        int krow = nk*16 + lr;
        bf16x8 bk = *(const bf16x8*)&k_sh[krow*DD + ((c & ~7) | ((c ^ krow)&7))*8];
        s[nk] = __builtin_amdgcn_mfma_f32_16x16x32_bf16(qf[ks], bk, s[nk], 0,0,0);
      }
    }
    // mask cols >= M (per-lane uniform per nk)
    #pragma unroll
    for (int nk=0; nk<2; nk++){
      if (kt*32 + nk*16 + lr >= M){
        s[nk][0] = -INFINITY; s[nk][1] = -INFINITY; s[nk][2] = -INFINITY; s[nk][3] = -INFINITY;
      }
    }
    // online softmax state (rows kg*4+r, local to wave)
    float al[4];
    #pragma unroll
    for (int r=0;r<4;r++){
      float v = fmaxf(s[0][r], s[1][r]);
      v = fmaxf(v, __shfl_xor(v, 1, 64));
      v = fmaxf(v, __shfl_xor(v, 2, 64));
      v = fmaxf(v, __shfl_xor(v, 4, 64));
      v = fmaxf(v, __shfl_xor(v, 8, 64));
      float mn = fmaxf(m_run[r], v);
      al[r] = __expf(m_run[r] - mn);
      m_run[r] = mn;
    }
    #pragma unroll
    for (int nk=0;nk<2;nk++)
      #pragma unroll
      for (int r=0;r<4;r++)
        s[nk][r] = __expf(s[nk][r] - m_run[r]);
    #pragma unroll
    for (int r=0;r<4;r++){
      float v = s[0][r] + s[1][r];
      v += __shfl_xor(v, 1, 64);
      v += __shfl_xor(v, 2, 64);
      v += __shfl_xor(v, 4, 64);
      v += __shfl_xor(v, 8, 64);
      l_run[r] = al[r]*l_run[r] + v;
    }
    // write P (C-layout lanes) to p_sh in A-layout rows
    #pragma unroll
    for (int nk=0;nk<2;nk++)
      #pragma unroll
      for (int r=0;r<4;r++)
        p_sh[(wv*16 + kg*4 + r)*56 + nk*16 + lr] = f2bf(s[nk][r]);
    // rescale O
    #pragma unroll
    for (int ni=0;ni<24;ni++)
      #pragma unroll
      for (int r=0;r<4;r++) O[ni][r] *= al[r];
    __syncthreads();   // p_sh visible (cross-lane)

    // PV: A = p rows wv*16+lr (k = 32 keys, one MFMA k-step), B = v_sh
    bf16x8 ap = *(const bf16x8*)&p_sh[(wv*16 + lr)*56 + kg*8];
    #pragma unroll
    for (int ni=0;ni<24;ni++){
      int d = ni*16 + lr;
      bf16x8 bv = *(const bf16x8*)&v_sh[d*32 + ((kg ^ (d&3))*8)];
      O[ni] = __builtin_amdgcn_mfma_f32_16x16x32_bf16(ap, bv, O[ni], 0,0,0);
    }
  }

  // epilogue: normalize by l, then LN(an) — fully wave-local (row split)
  float inv[4];
  #pragma unroll
  for (int r=0;r<4;r++) inv[r] = 1.f / l_run[r];
  float s1[4] = {0,0,0,0}, s2[4] = {0,0,0,0};
  #pragma unroll
  for (int ni=0;ni<24;ni++)
    #pragma unroll
    for (int r=0;r<4;r++){
      float x = O[ni][r]*inv[r];
      O[ni][r] = x;
      s1[r] += x; s2[r] += x*x;
    }
  #pragma unroll
  for (int r=0;r<4;r++){
    #pragma unroll
    for (int o=1;o<16;o<<=1){ s1[r] += __shfl_xor(s1[r], o, 64); s2[r] += __shfl_xor(s2[r], o, 64); }
  }
  float mu[4], rs[4];
  #pragma unroll
  for (int r=0;r<4;r++){
    mu[r] = s1[r]*(1.f/DD);
    float var = s2[r]*(1.f/DD) - mu[r]*mu[r];
    rs[r] = rsqrtf(fmaxf(var, 0.f) + 1e-6f);
  }
  int rowb = qt0 + wv*16 + kg*4;
  #pragma unroll
  for (int ni=0;ni<24;ni++){
    int col = ni*16 + lr;
    float wc = anw[col], bc = anb[col];
    #pragma unroll
    for (int r=0;r<4;r++){
      int qrow = rowb + r;
      if (qrow < NN)
        out[((size_t)b*NN + qrow)*DD + col] = f2bf((O[ni][r]-mu[r])*rs[r]*wc + bc);
    }
  }
}

// ---------------- launcher ----------------

extern "C" void kernel_launch(void* const* d_in, const int* in_sizes, int n_in,
                              void* d_out, int out_size, void* d_ws, size_t ws_size,
                              hipStream_t stream){
  const float* x_in = (const float*)d_in[0];
  const float* n1w  = (const float*)d_in[1];
  const float* n1b  = (const float*)d_in[2];
  const float* qkvw = (const float*)d_in[3];
  const float* qkvb = (const float*)d_in[4];
  const float* qnw  = (const float*)d_in[5];
  const float* qnb  = (const float*)d_in[6];
  const float* knw  = (const float*)d_in[7];
  const float* knb  = (const float*)d_in[8];
  const float* anw  = (const float*)d_in[9];
  const float* anb  = (const float*)d_in[10];
  const float* pw   = (const float*)d_in[11];
  const float* pb   = (const float*)d_in[12];
  const float* ls1  = (const float*)d_in[13];
  const float* n2w  = (const float*)d_in[14];
  const float* n2b  = (const float*)d_in[15];
  const float* f1w  = (const float*)d_in[16];
  const float* f1b  = (const float*)d_in[17];
  const float* f2w  = (const float*)d_in[18];
  const float* f2bb = (const float*)d_in[19];
  const float* ls2  = (const float*)d_in[20];

  char* ws = (char*)d_ws;
  size_t off = 0;
  auto alloc = [&](size_t bytes)->char* {
    char* p = ws + off;
    off = (off + bytes + 255) & ~(size_t)255;
    return p;
  };

  const int QKV = 3*DD*DD, PRJ = DD*DD, F1 = HD*DD;
  const size_t WTOT = (size_t)QKV + PRJ + 2*F1;
  const size_t SLOT = (size_t)BB*MP*DD;

  unsigned short* wbuf  = (unsigned short*)alloc(WTOT*2);
  float*          cls_h = (float*)         alloc((size_t)NRPT*BB*DD*4);
  unsigned short* mem_bf= (unsigned short*)alloc(SLOT*2);
  unsigned short* pool  = (unsigned short*)alloc(6*SLOT*2);

  unsigned short* wq = wbuf;
  unsigned short* wp = wbuf + QKV;
  unsigned short* w1 = wbuf + QKV + PRJ;
  unsigned short* w2 = wbuf + QKV + PRJ + F1;

  unsigned short* S0 = pool;
  unsigned short* S1 = pool + SLOT;
  unsigned short* S2 = pool + 2*SLOT;
  unsigned short* S3 = pool + 3*SLOT;
  unsigned short* S4 = pool + 4*SLOT;
  unsigned short* S5 = pool + 5*SLOT;

  unsigned short* xn    = S0;   // ln1 out        (1-2)
  unsigned short* qraw  = S1;   // q gemm out     (2-5)
  unsigned short* kraw  = S2;   // k gemm out     (3-5)
  unsigned short* qb    = S3;   // lnqk q out     (5-6)
  unsigned short* kb    = S4;   // lnqk k out     (5-6)
  unsigned short* vT    = S5;   // vT gemm out    (4-6)
  unsigned short* prodn = S1;   // attn out       (6-7)
  unsigned short* x2    = S0;   // ln2 out        (8-9)
  unsigned short* h     = S1;   // fc1 out S1..S4 (9-10)

  float* xf = (float*)d_out;

  auto cg = [](size_t n){ return dim3((unsigned)((n + 255) / 256)); };

  hipMemcpyAsync(xf, x_in, (size_t)BB*NN*DD*4, hipMemcpyDeviceToDevice, stream);

  const int RT  = (BB*NN + 127)/128;
  const int RTM = (BB*MP)/128;
  const int QR  = BB*NN;
  const int KR  = BB*MP;

  for (int r = 0; r < NRPT; r++){
    int M = NN + r;
    prep_k<<<cg((size_t)BB*MP*DD),256,0,stream>>>(xf, x_in, cls_h + (size_t)r*BB*DD, cls_h, mem_bf, r);
    for (int l = 0; l < LL; l++){
      castL_k<<<cg(WTOT),256,0,stream>>>(qkvw + (size_t)l*QKV, pw + (size_t)l*PRJ,
                                         f1w + (size_t)l*F1, f2w + (size_t)l*F1, wbuf);
      ln4_k<float><<<cg((size_t)QR*64),256,0,stream>>>(xf, n1w + l*DD, n1b + l*DD, xn, QR);
      gemm128<0><<<dim3(3,RT,1),256,0,stream>>>(xn,384,QR,0, wq,384,384,0,
          qkvb + l*3*DD, 384,384, nullptr,qraw,384,QR,0, nullptr);
      gemm128<0><<<dim3(3,RTM,1),256,0,stream>>>(mem_bf,384,KR,0, wq + (size_t)DD*DD,384,384,0,
          qkvb + l*3*DD + DD, 384,384, nullptr,kraw,384,KR,0, nullptr);
      gemm128<1><<<dim3(MP/128,3,BB),256,0,stream>>>(wq + (size_t)2*DD*DD,384,384,0, mem_bf,384,MP,(long)MP*DD,
          qkvb + l*3*DD + 2*DD, 384,MP, nullptr,vT,MP,384,(long)DD*MP, nullptr);
      lnqk_k<<<(QR+KR)/4,256,0,stream>>>(qraw, kraw, qnw + l*DD, qnb + l*DD,
                                         knw + l*DD, knb + l*DD, qb, kb);
      attn_k<<<dim3(10,BB),256,0,stream>>>(qb, kb, vT, anw + l*DD, anb + l*DD, prodn, M);
      gemm128<2><<<dim3(3,RT,1),256,0,stream>>>(prodn,384,QR,0, wp,384,384,0,
          pb + l*DD, 384,384, xf,nullptr,384,QR,0, ls1 + l*DD);
      ln4_k<float><<<cg((size_t)QR*64),256,0,stream>>>(xf, n2w + l*DD, n2b + l*DD, x2, QR);
      gemm128<3><<<dim3(HD/128,RT,1),256,0,stream>>>(x2,384,QR,0, w1,384,HD,0,
          f1b + l*HD, 384,HD, nullptr,h,HD,QR,0, nullptr);
      gemm128<2><<<dim3(3,RT,1),256,0,stream>>>(h,HD,QR,0, w2,HD,384,0,
          f2bb + l*DD, HD,384, xf,nullptr,384,QR,0, ls2 + l*DD);
    }
  }
}